// Round 12
// baseline (228.854 us; speedup 1.0000x reference)
//
#include <hip/hip_runtime.h>
#include <hip/hip_bf16.h>
#include <stdint.h>

#define B_ 8
#define C_ 512
#define N_ 2048
#define H_ 8
#define D_ 64
#define HID_ 512

typedef short bf16x8 __attribute__((ext_vector_type(8)));
typedef float f32x4 __attribute__((ext_vector_type(4)));
typedef short short4v __attribute__((ext_vector_type(4)));

__device__ __forceinline__ float bf2f(unsigned short v) {
  union { float f; unsigned u; } c; c.u = ((unsigned)v) << 16; return c.f;
}
__device__ __forceinline__ unsigned short f2bf(float f) {
  union { float f; unsigned u; } c; c.f = f;
  unsigned u = c.u + 0x7FFFu + ((c.u >> 16) & 1u);
  return (unsigned short)(u >> 16);
}

// SESSION RULES:
//  - (R3/R6/R8, all ~0.1 absmax): no raw inline asm adjacent to TRANS-op
//    (v_exp) dataflow — INLINEASM defeats TRANS wait-state insertion.
//  - (R11 compile fail): no arrays of LDS pointers (addrspacecast init
//    unsupported); select __shared__ buffers via explicit ternaries.

// async global->LDS, 16B per lane. LDS dest is wave-uniform base + lane*16;
// any swizzle must be applied on the GLOBAL source address.
__device__ __forceinline__ void async_copy16(const void* g, void* l) {
  __builtin_amdgcn_global_load_lds((const __attribute__((address_space(1))) void*)g,
                                   (__attribute__((address_space(3))) void*)l,
                                   16, 0, 0);
}

// ---------------------------------------------------------------------------
// Kernel 1: channel LayerNorm + transpose, SINGLE global read of x.
// Absorbs the weight f32->bf16 conversion (hidden under the slab DMA).
// ---------------------------------------------------------------------------
__global__ __launch_bounds__(256) void ln_transpose(
    const float* __restrict__ x,            // (B, C, N) f32
    const float* __restrict__ g,            // (C,) f32
    unsigned short* __restrict__ xnt,       // (B, N, C) bf16
    const float* __restrict__ Ws1, unsigned short* __restrict__ Wd1, int n1,
    const float* __restrict__ Ws2, unsigned short* __restrict__ Wd2, int n2) {
  __shared__ __align__(16) float slab[C_ * 64];            // [c][n], 128 KB
  __shared__ __align__(16) unsigned short tile2[64 * 65];  // [c-chunk][n] bf16
  __shared__ float red[256], red2[256];
  __shared__ float meanS[64], rstdS[64];

  const int b = blockIdx.y, n0 = blockIdx.x * 64;
  const int t = threadIdx.x;
  const float* xb = x + (size_t)b * C_ * N_ + n0;

  // phase 1: DMA the slab (16 lanes per c-row, 4 f32/lane)
#pragma unroll
  for (int call = 0; call < 32; ++call) {
    int c = call * 16 + (t >> 4);
    async_copy16(&xb[(size_t)c * N_ + (t & 15) * 4], &slab[call * 1024 + t * 4]);
  }

  // weight conversion (former wcvt2), overlapped with the slab DMA
  {
    const int bid = blockIdx.y * gridDim.x + blockIdx.x;  // 0..255
    for (int i = bid * 256 + t; i < n1 + n2; i += 256 * 256) {
      const float4 v = (i < n1) ? ((const float4*)Ws1)[i] : ((const float4*)Ws2)[i - n1];
      short4v pk;
      pk[0] = (short)f2bf(v.x); pk[1] = (short)f2bf(v.y);
      pk[2] = (short)f2bf(v.z); pk[3] = (short)f2bf(v.w);
      if (i < n1) ((short4v*)Wd1)[i] = pk; else ((short4v*)Wd2)[i - n1] = pk;
    }
  }

  asm volatile("s_waitcnt vmcnt(0)" ::: "memory");
  __syncthreads();

  // phase 2: stats — 4 c-partials per n (lanes vary n: 2-way, free)
  {
    const int n = t & 63, cb = (t >> 6) * 128;
    float s = 0.f, s2 = 0.f;
    for (int c = cb; c < cb + 128; ++c) {
      float v = slab[c * 64 + n];
      s += v; s2 += v * v;
    }
    red[t] = s; red2[t] = s2;
  }
  __syncthreads();
  if (t < 64) {
    float ts  = red[t]  + red[t + 64]  + red[t + 128]  + red[t + 192];
    float ts2 = red2[t] + red2[t + 64] + red2[t + 128] + red2[t + 192];
    float mean = ts * (1.0f / C_);
    float var  = ts2 * (1.0f / C_) - mean * mean;
    meanS[t] = mean;
    rstdS[t] = rsqrtf(var + 1e-5f);
  }
  __syncthreads();

  unsigned short* xout = xnt + ((size_t)b * N_ + n0) * C_;
  for (int c0 = 0; c0 < C_; c0 += 64) {
    // normalize into padded tile (lanes vary n: conflict-free)
    for (int e = t; e < 64 * 64; e += 256) {
      int cl = e >> 6, nl = e & 63;
      float v = slab[(c0 + cl) * 64 + nl];
      tile2[cl * 65 + nl] = f2bf((v - meanS[nl]) * rstdS[nl] * g[c0 + cl]);
    }
    __syncthreads();
    // transposed write: 4 c per lane, consecutive lanes -> consecutive c
    for (int e = t; e < 64 * 16; e += 256) {
      int nl = e >> 4, c4 = (e & 15) * 4;
      short4v pk;
#pragma unroll
      for (int j = 0; j < 4; ++j) pk[j] = (short)tile2[(c4 + j) * 65 + nl];
      *(short4v*)&xout[(size_t)nl * C_ + c0 + c4] = pk;
    }
    __syncthreads();
  }
}

// ---------------------------------------------------------------------------
// Kernel 2: QKV GEMM, 128x128 tile, BK=32 double-buffered 2-phase prefetch.
// Epilogue: q*0.125 -> (b,h,n,d); k -> (b,h,n,d); v -> (b,h,d,n) with the
// sigma j-permutation for attn's single-b128 PV reads.
// ---------------------------------------------------------------------------
__global__ __launch_bounds__(256) void qkv_gemm(
    const unsigned short* __restrict__ W,    // (1536, 512) bf16
    const unsigned short* __restrict__ xnt,  // (B, N, C) bf16
    unsigned short* __restrict__ qt,
    unsigned short* __restrict__ kt,
    unsigned short* __restrict__ vt) {
  __shared__ __align__(16) short As[2][128 * 32];
  __shared__ __align__(16) short Bs[2][128 * 32];

  const int n0 = blockIdx.x * 128, m0 = blockIdx.y * 128, b = blockIdx.z;
  const int t = threadIdx.x;
  const int lane = t & 63, wave = t >> 6;
  const int col = lane & 15, quad = lane >> 4;
  const int wRow = (wave >> 1) * 64, wCol = (wave & 1) * 64;
  const unsigned short* xb = xnt + (size_t)b * N_ * C_;
  const int ldr = t >> 2;                        // 0..63: row within 64-row chunk
  const int ldc8 = (((t & 3) ^ (ldr & 3)) * 8);  // swizzled 8-short chunk
  const int kc = (quad ^ (col & 3)) * 8;         // read chunk (undoes swizzle)

  f32x4 acc[4][4] = {};

  // prologue: stage K-tile 0 into buffers 0
#pragma unroll
  for (int call = 0; call < 2; ++call) {
    async_copy16(&W[(size_t)(m0 + call * 64 + ldr) * C_ + ldc8],
                 &As[0][call * 2048 + t * 8]);
    async_copy16(&xb[(size_t)(n0 + call * 64 + ldr) * C_ + ldc8],
                 &Bs[0][call * 2048 + t * 8]);
  }
  asm volatile("s_waitcnt vmcnt(0)" ::: "memory");
  __syncthreads();

  int p = 0;
  for (int k0 = 0; k0 < C_; k0 += 32) {
    if (k0 + 32 < C_) {
#pragma unroll
      for (int call = 0; call < 2; ++call) {
        async_copy16(&W[(size_t)(m0 + call * 64 + ldr) * C_ + k0 + 32 + ldc8],
                     &As[p ^ 1][call * 2048 + t * 8]);
        async_copy16(&xb[(size_t)(n0 + call * 64 + ldr) * C_ + k0 + 32 + ldc8],
                     &Bs[p ^ 1][call * 2048 + t * 8]);
      }
    }
    bf16x8 a[4], bb[4];
#pragma unroll
    for (int i = 0; i < 4; ++i)
      a[i] = *(const bf16x8*)&As[p][(wRow + i * 16 + col) * 32 + kc];
#pragma unroll
    for (int j = 0; j < 4; ++j)
      bb[j] = *(const bf16x8*)&Bs[p][(wCol + j * 16 + col) * 32 + kc];
#pragma unroll
    for (int i = 0; i < 4; ++i)
#pragma unroll
      for (int j = 0; j < 4; ++j)
        acc[i][j] = __builtin_amdgcn_mfma_f32_16x16x32_bf16(a[i], bb[j], acc[i][j], 0, 0, 0);
    asm volatile("s_waitcnt vmcnt(0)" ::: "memory");  // prefetch landed
    __syncthreads();                                  // all reads of p done
    p ^= 1;
  }

  const int sect = m0 >> 9;
  const int mloc = (m0 & 511) + wRow;
  const int h = mloc >> 6;
  if (sect < 2) {
    unsigned short* dst = (sect == 0 ? qt : kt) + ((size_t)b * H_ + h) * N_ * D_;
    const float scl = (sect == 0) ? 0.125f : 1.0f;  // pow2 = exact in bf16
#pragma unroll
    for (int i = 0; i < 4; ++i) {
      int d0 = i * 16 + quad * 4;
#pragma unroll
      for (int j = 0; j < 4; ++j) {
        int n = n0 + wCol + j * 16 + col;
        short4v pk;
#pragma unroll
        for (int r = 0; r < 4; ++r) pk[r] = (short)f2bf(acc[i][j][r] * scl);
        *(short4v*)&dst[(size_t)n * D_ + d0] = pk;
      }
    }
  } else {
    unsigned short* dst = vt + ((size_t)b * H_ + h) * D_ * N_;
    // within-64-block j-permutation: off=j*16+col ->
    //   p = 32*(j>>1) + 8*(col>>2) + 4*(j&1) + (col&3)   (bijective)
    const int pcol = 8 * (col >> 2) + (col & 3);
#pragma unroll
    for (int i = 0; i < 4; ++i) {
      int d0 = i * 16 + quad * 4;
#pragma unroll
      for (int j = 0; j < 4; ++j) {
        int n = n0 + wCol + 32 * (j >> 1) + 4 * (j & 1) + pcol;
#pragma unroll
        for (int r = 0; r < 4; ++r)
          dst[(size_t)(d0 + r) * N_ + n] = f2bf(acc[i][j][r]);
      }
    }
  }
}

// ---------------------------------------------------------------------------
// Kernel 3: flash attention. Round-12 = Round-11 design, compile-fixed (no
// LDS-pointer arrays). R10 counters showed LDS-read-bound (~44 us/CU LDS-read
// vs ~37 us MFMA: 16 b128 reads fed only 36 MFMA/wave-tile). Restructure:
// BQ=256 as 4 waves x 64 q-rows (256 threads, i=4) — same 16 reads feed 72
// MFMA (ratio 0.44->0.22), LDS-read time halves, kernel becomes MFMA-bound.
// St held to [4][2] by interleaving S(jtl-pair)->PV per ks-half.
// __launch_bounds__(256,2): ~185 est VGPR < 256 cap; 2 waves/SIMD (HBM
// latency hidden by the full-iteration prefetch skeleton).
// All layout algebra (swizzles, sigma, epilogue) unchanged from R9-proven.
// ---------------------------------------------------------------------------
__global__ __launch_bounds__(256, 2) void attn(
    const unsigned short* __restrict__ qt,   // (B,H,N,D), pre-scaled
    const unsigned short* __restrict__ kt,   // (B,H,N,D)
    const unsigned short* __restrict__ vt,   // (B,H,D,N) j-permuted
    unsigned short* __restrict__ aot) {      // (B,N,HID)
  __shared__ __align__(16) short Kb[2][64 * 64];      // (j,d) swizzled, dbuf
  __shared__ __align__(16) short Vb[2][64 * 64];      // (d,j-perm) swizzled, dbuf

  const int q0 = blockIdx.x * 256;
  const int bh = blockIdx.y;
  const int t = threadIdx.x, lane = t & 63, wave = t >> 6;
  const int col = lane & 15, quad = lane >> 4;
  const int cs = col & 7;
  const unsigned short* qp = qt + (size_t)bh * N_ * D_;
  const unsigned short* kp = kt + (size_t)bh * N_ * D_;
  const unsigned short* vp = vt + (size_t)bh * D_ * N_;
  const int r8 = t >> 3;                     // 0..31: row within a 32-row half
  const int c8 = (((t & 7) ^ (r8 & 7)) * 8); // swizzled 8-short column chunk
  // (row+32 has the same &7, so both halves share the chunk pattern)

  // stage Q (256x64, swizzled) across all four buffers (explicit, no ptr array)
#pragma unroll
  for (int half = 0; half < 2; ++half) {
    async_copy16(&qp[(size_t)(q0 +   0 + half * 32 + r8) * D_ + c8], &Kb[0][half * 2048 + t * 8]);
    async_copy16(&qp[(size_t)(q0 +  64 + half * 32 + r8) * D_ + c8], &Kb[1][half * 2048 + t * 8]);
    async_copy16(&qp[(size_t)(q0 + 128 + half * 32 + r8) * D_ + c8], &Vb[0][half * 2048 + t * 8]);
    async_copy16(&qp[(size_t)(q0 + 192 + half * 32 + r8) * D_ + c8], &Vb[1][half * 2048 + t * 8]);
  }
  asm volatile("s_waitcnt vmcnt(0)" ::: "memory");
  __syncthreads();
  // wave w owns q-rows 64w..64w+63 = exactly buffer w (ternary select: R11 rule)
  const short* Qsrc = (wave == 0) ? Kb[0] : (wave == 1) ? Kb[1]
                    : (wave == 2) ? Vb[0] : Vb[1];
  bf16x8 qf[4][2];
#pragma unroll
  for (int i = 0; i < 4; ++i)
#pragma unroll
    for (int ks = 0; ks < 2; ++ks)
      qf[i][ks] = *(const bf16x8*)&Qsrc[(i * 16 + col) * 64 + ((ks * 4 + quad) ^ cs) * 8];
  __syncthreads();  // all Q fragment reads done before K/V overwrite

  // K(0) -> Kb[0], V(0) -> Vb[0]
#pragma unroll
  for (int half = 0; half < 2; ++half) {
    async_copy16(&kp[(size_t)(half * 32 + r8) * D_ + c8], &Kb[0][half * 2048 + t * 8]);
    async_copy16(&vp[(size_t)(half * 32 + r8) * N_ + c8], &Vb[0][half * 2048 + t * 8]);
  }
  asm volatile("s_waitcnt vmcnt(0)" ::: "memory");
  __syncthreads();

  bf16x8 onesb;
#pragma unroll
  for (int j = 0; j < 8; ++j) onesb[j] = (short)0x3F80;  // bf16 1.0

  f32x4 O[4][4] = {};
  f32x4 L[4] = {};

  int p = 0;
  for (int j0 = 0; j0 < N_; j0 += 64) {
    // prefetch next K/V tile into the alternate buffers; waited at iter tail
    if (j0 + 64 < N_) {
#pragma unroll
      for (int half = 0; half < 2; ++half) {
        async_copy16(&kp[(size_t)(j0 + 64 + half * 32 + r8) * D_ + c8],
                     &Kb[p ^ 1][half * 2048 + t * 8]);
        async_copy16(&vp[(size_t)(half * 32 + r8) * N_ + (j0 + 64) + c8],
                     &Vb[p ^ 1][half * 2048 + t * 8]);
      }
    }
    const short* Kc = Kb[p];
    const short* Vc = Vb[p];

    f32x4 St[4][2];
#pragma unroll
    for (int ks = 0; ks < 2; ++ks) {
      // S^T for this j-half: jtl pair (2ks, 2ks+1); accumulate over ksd (K=64)
#pragma unroll
      for (int i = 0; i < 4; ++i)
#pragma unroll
        for (int jt = 0; jt < 2; ++jt)
          St[i][jt] = (f32x4){0.f, 0.f, 0.f, 0.f};
#pragma unroll
      for (int jt = 0; jt < 2; ++jt) {
#pragma unroll
        for (int ksd = 0; ksd < 2; ++ksd) {
          bf16x8 kb = *(const bf16x8*)&Kc[((ks * 2 + jt) * 16 + col) * 64 + ((ksd * 4 + quad) ^ cs) * 8];
#pragma unroll
          for (int i = 0; i < 4; ++i)
            St[i][jt] = __builtin_amdgcn_mfma_f32_16x16x32_bf16(kb, qf[i][ksd], St[i][jt], 0, 0, 0);
        }
      }
      // PV for this j-half: pa = lane's own exp'd values (sigma k-order),
      // packed via __float22bfloat162_rn; B = one b128 from permuted V.
      bf16x8 pa[4];
#pragma unroll
      for (int i = 0; i < 4; ++i) {
        union { bf16x8 v; unsigned u[4]; } pk;
#pragma unroll
        for (int w = 0; w < 4; ++w) {
          float lo = __expf(St[i][w >> 1][2 * (w & 1) + 0]);
          float hi = __expf(St[i][w >> 1][2 * (w & 1) + 1]);
          __hip_bfloat162 h2 = __float22bfloat162_rn(make_float2(lo, hi));
          __builtin_memcpy(&pk.u[w], &h2, 4);
        }
        pa[i] = pk.v;
      }
#pragma unroll
      for (int dt = 0; dt < 4; ++dt) {
        bf16x8 vb = *(const bf16x8*)&Vc[(dt * 16 + col) * 64 + ((ks * 4 + quad) ^ cs) * 8];
#pragma unroll
        for (int i = 0; i < 4; ++i)
          O[i][dt] = __builtin_amdgcn_mfma_f32_16x16x32_bf16(pa[i], vb, O[i][dt], 0, 0, 0);
      }
#pragma unroll
      for (int i = 0; i < 4; ++i)
        L[i] = __builtin_amdgcn_mfma_f32_16x16x32_bf16(pa[i], onesb, L[i], 0, 0, 0);
    }

    asm volatile("s_waitcnt vmcnt(0)" ::: "memory");  // prefetch landed
    __syncthreads();         // all reads of buffers p done block-wide
    p ^= 1;
  }

  // epilogue: normalize by l, write ao_t[b][n][h*64+d]
  const int b = bh >> 3, h = bh & 7;
  unsigned short* ob = aot + (size_t)b * N_ * HID_;
#pragma unroll
  for (int i = 0; i < 4; ++i) {
#pragma unroll
    for (int r = 0; r < 4; ++r) {
      int n = q0 + wave * 64 + i * 16 + quad * 4 + r;
      float inv = 1.0f / L[i][r];
#pragma unroll
      for (int dt = 0; dt < 4; ++dt)
        ob[(size_t)n * HID_ + h * 64 + dt * 16 + col] = f2bf(O[i][dt][r] * inv);
    }
  }
}

// ---------------------------------------------------------------------------
// Kernel 4: out GEMM, BK=32 double-buffered 2-phase prefetch.
// ---------------------------------------------------------------------------
__global__ __launch_bounds__(256) void out_gemm(
    const unsigned short* __restrict__ W,    // (512, 512) bf16
    const unsigned short* __restrict__ aot,  // (B, N, HID) bf16
    const float* __restrict__ bias,          // (512,) f32
    float* __restrict__ out) {               // (B, C, N) f32
  __shared__ __align__(16) short As[2][128 * 32];
  __shared__ __align__(16) short Bs[2][128 * 32];

  const int n0 = blockIdx.x * 128, m0 = blockIdx.y * 128, b = blockIdx.z;
  const int t = threadIdx.x;
  const int lane = t & 63, wave = t >> 6;
  const int col = lane & 15, quad = lane >> 4;
  const int wRow = (wave >> 1) * 64, wCol = (wave & 1) * 64;
  const unsigned short* xb = aot + (size_t)b * N_ * HID_;
  const int ldr = t >> 2;
  const int ldc8 = (((t & 3) ^ (ldr & 3)) * 8);
  const int kc = (quad ^ (col & 3)) * 8;

  f32x4 acc[4][4] = {};

#pragma unroll
  for (int call = 0; call < 2; ++call) {
    async_copy16(&W[(size_t)(m0 + call * 64 + ldr) * HID_ + ldc8],
                 &As[0][call * 2048 + t * 8]);
    async_copy16(&xb[(size_t)(n0 + call * 64 + ldr) * HID_ + ldc8],
                 &Bs[0][call * 2048 + t * 8]);
  }
  asm volatile("s_waitcnt vmcnt(0)" ::: "memory");
  __syncthreads();

  int p = 0;
  for (int k0 = 0; k0 < HID_; k0 += 32) {
    if (k0 + 32 < HID_) {
#pragma unroll
      for (int call = 0; call < 2; ++call) {
        async_copy16(&W[(size_t)(m0 + call * 64 + ldr) * HID_ + k0 + 32 + ldc8],
                     &As[p ^ 1][call * 2048 + t * 8]);
        async_copy16(&xb[(size_t)(n0 + call * 64 + ldr) * HID_ + k0 + 32 + ldc8],
                     &Bs[p ^ 1][call * 2048 + t * 8]);
      }
    }
    bf16x8 a[4], bb[4];
#pragma unroll
    for (int i = 0; i < 4; ++i)
      a[i] = *(const bf16x8*)&As[p][(wRow + i * 16 + col) * 32 + kc];
#pragma unroll
    for (int j = 0; j < 4; ++j)
      bb[j] = *(const bf16x8*)&Bs[p][(wCol + j * 16 + col) * 32 + kc];
#pragma unroll
    for (int i = 0; i < 4; ++i)
#pragma unroll
      for (int j = 0; j < 4; ++j)
        acc[i][j] = __builtin_amdgcn_mfma_f32_16x16x32_bf16(a[i], bb[j], acc[i][j], 0, 0, 0);
    asm volatile("s_waitcnt vmcnt(0)" ::: "memory");
    __syncthreads();
    p ^= 1;
  }

#pragma unroll
  for (int i = 0; i < 4; ++i) {
#pragma unroll
    for (int r = 0; r < 4; ++r) {
      int m = m0 + wRow + i * 16 + quad * 4 + r;
      float bv = bias[m];
#pragma unroll
      for (int j = 0; j < 4; ++j) {
        int n = n0 + wCol + j * 16 + col;
        out[((size_t)b * C_ + m) * N_ + n] = acc[i][j][r] + bv;
      }
    }
  }
}

extern "C" void kernel_launch(void* const* d_in, const int* in_sizes, int n_in,
                              void* d_out, int out_size, void* d_ws, size_t ws_size,
                              hipStream_t stream) {
  const float* x    = (const float*)d_in[0];
  const float* g    = (const float*)d_in[1];
  const float* Wqkv = (const float*)d_in[2];
  const float* Wout = (const float*)d_in[3];
  const float* bout = (const float*)d_in[4];
  float* out = (float*)d_out;

  unsigned short* ws  = (unsigned short*)d_ws;
  unsigned short* xnt = ws;                                  // B*N*C
  unsigned short* qt  = xnt + (size_t)B_ * N_ * C_;
  unsigned short* kt  = qt  + (size_t)B_ * H_ * N_ * D_;
  unsigned short* vt  = kt  + (size_t)B_ * H_ * N_ * D_;
  unsigned short* aot = vt  + (size_t)B_ * H_ * D_ * N_;     // B*N*HID
  unsigned short* Wqb = aot + (size_t)B_ * N_ * HID_;        // 1536*512
  unsigned short* Wob = Wqb + (size_t)3 * HID_ * C_;         // 512*512

  ln_transpose<<<dim3(N_ / 64, B_), 256, 0, stream>>>(
      x, g, xnt, Wqkv, Wqb, 3 * HID_ * C_ / 4, Wout, Wob, C_ * HID_ / 4);
  qkv_gemm<<<dim3(N_ / 128, 12, B_), 256, 0, stream>>>(Wqb, xnt, qt, kt, vt);
  attn<<<dim3(N_ / 256, B_ * H_), 256, 0, stream>>>(qt, kt, vt, aot);
  out_gemm<<<dim3(N_ / 128, 4, B_), 256, 0, stream>>>(Wob, aot, bout, out);
}

// Round 13
// 227.364 us; speedup vs baseline: 1.0066x; 1.0066x over previous
//
#include <hip/hip_runtime.h>
#include <hip/hip_bf16.h>
#include <stdint.h>

#define B_ 8
#define C_ 512
#define N_ 2048
#define H_ 8
#define D_ 64
#define HID_ 512

typedef short bf16x8 __attribute__((ext_vector_type(8)));
typedef float f32x4 __attribute__((ext_vector_type(4)));
typedef short short4v __attribute__((ext_vector_type(4)));

__device__ __forceinline__ float bf2f(unsigned short v) {
  union { float f; unsigned u; } c; c.u = ((unsigned)v) << 16; return c.f;
}
__device__ __forceinline__ unsigned short f2bf(float f) {
  union { float f; unsigned u; } c; c.f = f;
  unsigned u = c.u + 0x7FFFu + ((c.u >> 16) & 1u);
  return (unsigned short)(u >> 16);
}

// SESSION RULES:
//  - (R3/R6/R8, all ~0.1 absmax): no raw inline asm adjacent to TRANS-op
//    (v_exp) dataflow — INLINEASM defeats TRANS wait-state insertion.
//  - (R11 compile fail): no arrays of LDS pointers; use explicit ternaries.
//  - (R12): attn 8w x 32r and 4w x 64r both ~82-84 us — LDS-read BW is NOT
//    the attn limit; issue-mix/latency bound at ~85% combined issue.

// async global->LDS, 16B per lane. LDS dest is wave-uniform base + lane*16;
// any swizzle must be applied on the GLOBAL source address.
__device__ __forceinline__ void async_copy16(const void* g, void* l) {
  __builtin_amdgcn_global_load_lds((const __attribute__((address_space(1))) void*)g,
                                   (__attribute__((address_space(3))) void*)l,
                                   16, 0, 0);
}

// ---------------------------------------------------------------------------
// Kernel 1: channel LayerNorm + transpose, SINGLE global read of x.
// Absorbs the weight f32->bf16 conversion (hidden under the slab DMA).
// ---------------------------------------------------------------------------
__global__ __launch_bounds__(256) void ln_transpose(
    const float* __restrict__ x,            // (B, C, N) f32
    const float* __restrict__ g,            // (C,) f32
    unsigned short* __restrict__ xnt,       // (B, N, C) bf16
    const float* __restrict__ Ws1, unsigned short* __restrict__ Wd1, int n1,
    const float* __restrict__ Ws2, unsigned short* __restrict__ Wd2, int n2) {
  __shared__ __align__(16) float slab[C_ * 64];            // [c][n], 128 KB
  __shared__ __align__(16) unsigned short tile2[64 * 65];  // [c-chunk][n] bf16
  __shared__ float red[256], red2[256];
  __shared__ float meanS[64], rstdS[64];

  const int b = blockIdx.y, n0 = blockIdx.x * 64;
  const int t = threadIdx.x;
  const float* xb = x + (size_t)b * C_ * N_ + n0;

  // phase 1: DMA the slab (16 lanes per c-row, 4 f32/lane)
#pragma unroll
  for (int call = 0; call < 32; ++call) {
    int c = call * 16 + (t >> 4);
    async_copy16(&xb[(size_t)c * N_ + (t & 15) * 4], &slab[call * 1024 + t * 4]);
  }

  // weight conversion (former wcvt2), overlapped with the slab DMA
  {
    const int bid = blockIdx.y * gridDim.x + blockIdx.x;  // 0..255
    for (int i = bid * 256 + t; i < n1 + n2; i += 256 * 256) {
      const float4 v = (i < n1) ? ((const float4*)Ws1)[i] : ((const float4*)Ws2)[i - n1];
      short4v pk;
      pk[0] = (short)f2bf(v.x); pk[1] = (short)f2bf(v.y);
      pk[2] = (short)f2bf(v.z); pk[3] = (short)f2bf(v.w);
      if (i < n1) ((short4v*)Wd1)[i] = pk; else ((short4v*)Wd2)[i - n1] = pk;
    }
  }

  asm volatile("s_waitcnt vmcnt(0)" ::: "memory");
  __syncthreads();

  // phase 2: stats — 4 c-partials per n (lanes vary n: 2-way, free)
  {
    const int n = t & 63, cb = (t >> 6) * 128;
    float s = 0.f, s2 = 0.f;
    for (int c = cb; c < cb + 128; ++c) {
      float v = slab[c * 64 + n];
      s += v; s2 += v * v;
    }
    red[t] = s; red2[t] = s2;
  }
  __syncthreads();
  if (t < 64) {
    float ts  = red[t]  + red[t + 64]  + red[t + 128]  + red[t + 192];
    float ts2 = red2[t] + red2[t + 64] + red2[t + 128] + red2[t + 192];
    float mean = ts * (1.0f / C_);
    float var  = ts2 * (1.0f / C_) - mean * mean;
    meanS[t] = mean;
    rstdS[t] = rsqrtf(var + 1e-5f);
  }
  __syncthreads();

  unsigned short* xout = xnt + ((size_t)b * N_ + n0) * C_;
  for (int c0 = 0; c0 < C_; c0 += 64) {
    // normalize into padded tile (lanes vary n: conflict-free)
    for (int e = t; e < 64 * 64; e += 256) {
      int cl = e >> 6, nl = e & 63;
      float v = slab[(c0 + cl) * 64 + nl];
      tile2[cl * 65 + nl] = f2bf((v - meanS[nl]) * rstdS[nl] * g[c0 + cl]);
    }
    __syncthreads();
    // transposed write: 4 c per lane, consecutive lanes -> consecutive c
    for (int e = t; e < 64 * 16; e += 256) {
      int nl = e >> 4, c4 = (e & 15) * 4;
      short4v pk;
#pragma unroll
      for (int j = 0; j < 4; ++j) pk[j] = (short)tile2[(c4 + j) * 65 + nl];
      *(short4v*)&xout[(size_t)nl * C_ + c0 + c4] = pk;
    }
    __syncthreads();
  }
}

// ---------------------------------------------------------------------------
// Kernel 2: QKV GEMM. Round-13: 256x128 tile (8 waves, 512 thr), BK=64,
// single-buffered with the R9-PROVEN staging/read pattern (8-row XOR swizzle,
// identical index algebra, just 4 A-calls + 2 B-calls per iter). Halves
// B-operand traffic + B LDS-reads per output and doubles MFMA per barrier
// (32/wave/iter). Grid (16, 6, 8) = 768 blocks = 3/CU; LDS 48 KB.
// Per-wave output 64x64 = one full head row-block: epilogue algebra unchanged
// (m0&511 + wRow still a multiple of 64).
// Epilogue: q*0.125 -> (b,h,n,d); k -> (b,h,n,d); v -> (b,h,d,n) with the
// sigma j-permutation for attn's single-b128 PV reads.
// ---------------------------------------------------------------------------
__global__ __launch_bounds__(512) void qkv_gemm(
    const unsigned short* __restrict__ W,    // (1536, 512) bf16
    const unsigned short* __restrict__ xnt,  // (B, N, C) bf16
    unsigned short* __restrict__ qt,
    unsigned short* __restrict__ kt,
    unsigned short* __restrict__ vt) {
  __shared__ __align__(16) short As[256 * 64];   // 32 KB
  __shared__ __align__(16) short Bs[128 * 64];   // 16 KB

  const int n0 = blockIdx.x * 128, m0 = blockIdx.y * 256, b = blockIdx.z;
  const int t = threadIdx.x;                 // 0..511
  const int lane = t & 63, wave = t >> 6;    // 8 waves
  const int col = lane & 15, quad = lane >> 4;
  const int wRow = (wave >> 1) * 64, wCol = (wave & 1) * 64;  // 4x2 wave grid
  const unsigned short* xb = xnt + (size_t)b * N_ * C_;
  const int ldr = t >> 3;                        // 0..63: row within 64-row chunk
  const int ldc8 = (((t & 7) ^ (ldr & 7)) * 8);  // swizzled 8-short chunk
  const int cs = col & 7;

  f32x4 acc[4][4] = {};

  for (int k0 = 0; k0 < C_; k0 += 64) {
    __syncthreads();
#pragma unroll
    for (int call = 0; call < 4; ++call)
      async_copy16(&W[(size_t)(m0 + call * 64 + ldr) * C_ + k0 + ldc8],
                   &As[call * 4096 + t * 8]);
#pragma unroll
    for (int call = 0; call < 2; ++call)
      async_copy16(&xb[(size_t)(n0 + call * 64 + ldr) * C_ + k0 + ldc8],
                   &Bs[call * 4096 + t * 8]);
    asm volatile("s_waitcnt vmcnt(0)" ::: "memory");
    __syncthreads();
#pragma unroll
    for (int ks = 0; ks < 2; ++ks) {
      const int kc = ((ks * 4 + quad) ^ cs) * 8;
      bf16x8 a[4], bb[4];
#pragma unroll
      for (int i = 0; i < 4; ++i)
        a[i] = *(const bf16x8*)&As[(wRow + i * 16 + col) * 64 + kc];
#pragma unroll
      for (int j = 0; j < 4; ++j)
        bb[j] = *(const bf16x8*)&Bs[(wCol + j * 16 + col) * 64 + kc];
#pragma unroll
      for (int i = 0; i < 4; ++i)
#pragma unroll
        for (int j = 0; j < 4; ++j)
          acc[i][j] = __builtin_amdgcn_mfma_f32_16x16x32_bf16(a[i], bb[j], acc[i][j], 0, 0, 0);
    }
  }

  const int sect = m0 >> 9;                  // 256-tile lies in one 512-section
  const int mloc = (m0 & 511) + wRow;        // multiple of 64
  const int h = mloc >> 6;
  if (sect < 2) {
    unsigned short* dst = (sect == 0 ? qt : kt) + ((size_t)b * H_ + h) * N_ * D_;
    const float scl = (sect == 0) ? 0.125f : 1.0f;  // pow2 = exact in bf16
#pragma unroll
    for (int i = 0; i < 4; ++i) {
      int d0 = i * 16 + quad * 4;
#pragma unroll
      for (int j = 0; j < 4; ++j) {
        int n = n0 + wCol + j * 16 + col;
        short4v pk;
#pragma unroll
        for (int r = 0; r < 4; ++r) pk[r] = (short)f2bf(acc[i][j][r] * scl);
        *(short4v*)&dst[(size_t)n * D_ + d0] = pk;
      }
    }
  } else {
    unsigned short* dst = vt + ((size_t)b * H_ + h) * D_ * N_;
    // within-64-block j-permutation: off=j*16+col ->
    //   p = 32*(j>>1) + 8*(col>>2) + 4*(j&1) + (col&3)   (bijective)
    const int pcol = 8 * (col >> 2) + (col & 3);
#pragma unroll
    for (int i = 0; i < 4; ++i) {
      int d0 = i * 16 + quad * 4;
#pragma unroll
      for (int j = 0; j < 4; ++j) {
        int n = n0 + wCol + 32 * (j >> 1) + 4 * (j & 1) + pcol;
#pragma unroll
        for (int r = 0; r < 4; ++r)
          dst[(size_t)(d0 + r) * N_ + n] = f2bf(acc[i][j][r]);
      }
    }
  }
}

// ---------------------------------------------------------------------------
// Kernel 3: flash attention — R9/R10-proven 8-wave x 32-q-row form (81.5 us)
// with one new zero-risk change: GRID AXES SWAPPED (x=bh, y=q-block) so
// bid = q*64 + bh and bid%8 = bh%8 — all 8 q-blocks of one (b,h) land on the
// SAME XCD (round-robin dispatch), sharing K/V in that XCD's L2.
// R12 FETCH was 139 MB vs 50 MB unique = 2.8x K/V re-fetch across XCDs;
// 8 live bh per XCD x 512 KB K/V = 4 MB = exactly one L2.
// ---------------------------------------------------------------------------
__global__ __launch_bounds__(512, 4) void attn(
    const unsigned short* __restrict__ qt,   // (B,H,N,D), pre-scaled
    const unsigned short* __restrict__ kt,   // (B,H,N,D)
    const unsigned short* __restrict__ vt,   // (B,H,D,N) j-permuted
    unsigned short* __restrict__ aot) {      // (B,N,HID)
  __shared__ __align__(16) short Kb[2][64 * 64];      // (j,d) swizzled, dbuf
  __shared__ __align__(16) short Vb[2][64 * 64];      // (d,j-perm) swizzled, dbuf

  const int bh = blockIdx.x;                 // XCD locality: bid%8 = bh%8
  const int q0 = blockIdx.y * 256;
  const int t = threadIdx.x, lane = t & 63, wave = t >> 6;
  const int col = lane & 15, quad = lane >> 4;
  const int cs = col & 7;
  const unsigned short* qp = qt + (size_t)bh * N_ * D_;
  const unsigned short* kp = kt + (size_t)bh * N_ * D_;
  const unsigned short* vp = vt + (size_t)bh * D_ * N_;
  const int r8 = t >> 3;                     // 0..63: row within a 64-row tile
  const int c8 = (((t & 7) ^ (r8 & 7)) * 8); // swizzled 8-short column chunk

  // stage Q (256x64, swizzled) across all four buffers; fragments -> regs
  async_copy16(&qp[(size_t)(q0 +   0 + r8) * D_ + c8], &Kb[0][t * 8]);
  async_copy16(&qp[(size_t)(q0 +  64 + r8) * D_ + c8], &Kb[1][t * 8]);
  async_copy16(&qp[(size_t)(q0 + 128 + r8) * D_ + c8], &Vb[0][t * 8]);
  async_copy16(&qp[(size_t)(q0 + 192 + r8) * D_ + c8], &Vb[1][t * 8]);
  asm volatile("s_waitcnt vmcnt(0)" ::: "memory");
  __syncthreads();
  const short* Qsrc = (wave < 2) ? Kb[0] : (wave < 4) ? Kb[1]
                    : (wave < 6) ? Vb[0] : Vb[1];
  const int qr0 = (wave & 1) * 32;  // global q-row of wave = wave*32
  bf16x8 qf[2][2];
#pragma unroll
  for (int i = 0; i < 2; ++i)
#pragma unroll
    for (int ks = 0; ks < 2; ++ks)
      qf[i][ks] = *(const bf16x8*)&Qsrc[(qr0 + i * 16 + col) * 64 + ((ks * 4 + quad) ^ cs) * 8];
  __syncthreads();  // all Q fragment reads done before K/V overwrite

  // K(0) -> Kb[0], V(0) -> Vb[0]
  async_copy16(&kp[(size_t)r8 * D_ + c8], &Kb[0][t * 8]);
  async_copy16(&vp[(size_t)r8 * N_ + c8], &Vb[0][t * 8]);
  asm volatile("s_waitcnt vmcnt(0)" ::: "memory");
  __syncthreads();

  bf16x8 onesb;
#pragma unroll
  for (int j = 0; j < 8; ++j) onesb[j] = (short)0x3F80;  // bf16 1.0

  f32x4 O[2][4] = {};
  f32x4 L[2] = {};

  int p = 0;
  for (int j0 = 0; j0 < N_; j0 += 64) {
    // prefetch next K/V tile into the alternate buffers; waited at iter tail
    if (j0 + 64 < N_) {
      async_copy16(&kp[(size_t)(j0 + 64 + r8) * D_ + c8], &Kb[p ^ 1][t * 8]);
      async_copy16(&vp[(size_t)r8 * N_ + (j0 + 64) + c8], &Vb[p ^ 1][t * 8]);
    }
    const short* Kc = Kb[p];
    const short* Vc = Vb[p];

    // S^T = mfma(K, Q): lane holds S[j = jtl*16 + quad*4 + r][q = i*16 + col]
    f32x4 St[2][4] = {};
#pragma unroll
    for (int jtl = 0; jtl < 4; ++jtl) {
#pragma unroll
      for (int ksd = 0; ksd < 2; ++ksd) {
        bf16x8 kb = *(const bf16x8*)&Kc[(jtl * 16 + col) * 64 + ((ksd * 4 + quad) ^ cs) * 8];
#pragma unroll
        for (int i = 0; i < 2; ++i)
          St[i][jtl] = __builtin_amdgcn_mfma_f32_16x16x32_bf16(kb, qf[i][ksd], St[i][jtl], 0, 0, 0);
      }
    }

    // PV: A-fragment = lane's own exp'd values (sigma k-order), packed via
    // __float22bfloat162_rn (compiler-visible); B = one b128 from permuted V.
#pragma unroll
    for (int ks = 0; ks < 2; ++ks) {
      bf16x8 pa[2];
#pragma unroll
      for (int i = 0; i < 2; ++i) {
        union { bf16x8 v; unsigned u[4]; } pk;
#pragma unroll
        for (int w = 0; w < 4; ++w) {
          // dword w holds elements e=2w (lo) and e=2w+1 (hi):
          //   e>>2 == w>>1, e&3 == 2*(w&1) + (e&1)
          float lo = __expf(St[i][2 * ks + (w >> 1)][2 * (w & 1) + 0]);
          float hi = __expf(St[i][2 * ks + (w >> 1)][2 * (w & 1) + 1]);
          __hip_bfloat162 h2 = __float22bfloat162_rn(make_float2(lo, hi));
          __builtin_memcpy(&pk.u[w], &h2, 4);
        }
        pa[i] = pk.v;
      }
#pragma unroll
      for (int dt = 0; dt < 4; ++dt) {
        bf16x8 vb = *(const bf16x8*)&Vc[(dt * 16 + col) * 64 + ((ks * 4 + quad) ^ cs) * 8];
#pragma unroll
        for (int i = 0; i < 2; ++i)
          O[i][dt] = __builtin_amdgcn_mfma_f32_16x16x32_bf16(pa[i], vb, O[i][dt], 0, 0, 0);
      }
#pragma unroll
      for (int i = 0; i < 2; ++i)
        L[i] = __builtin_amdgcn_mfma_f32_16x16x32_bf16(pa[i], onesb, L[i], 0, 0, 0);
    }

    asm volatile("s_waitcnt vmcnt(0)" ::: "memory");  // prefetch landed
    __syncthreads();         // all reads of buffers p done block-wide
    p ^= 1;
  }

  // epilogue: normalize by l, write ao_t[b][n][h*64+d]
  const int b = bh >> 3, h = bh & 7;
  unsigned short* ob = aot + (size_t)b * N_ * HID_;
#pragma unroll
  for (int i = 0; i < 2; ++i) {
#pragma unroll
    for (int r = 0; r < 4; ++r) {
      int n = q0 + wave * 32 + i * 16 + quad * 4 + r;
      float inv = 1.0f / L[i][r];
#pragma unroll
      for (int dt = 0; dt < 4; ++dt)
        ob[(size_t)n * HID_ + h * 64 + dt * 16 + col] = f2bf(O[i][dt][r] * inv);
    }
  }
}

// ---------------------------------------------------------------------------
// Kernel 4: out GEMM, BK=32 double-buffered 2-phase prefetch (unchanged).
// ---------------------------------------------------------------------------
__global__ __launch_bounds__(256) void out_gemm(
    const unsigned short* __restrict__ W,    // (512, 512) bf16
    const unsigned short* __restrict__ aot,  // (B, N, HID) bf16
    const float* __restrict__ bias,          // (512,) f32
    float* __restrict__ out) {               // (B, C, N) f32
  __shared__ __align__(16) short As[2][128 * 32];
  __shared__ __align__(16) short Bs[2][128 * 32];

  const int n0 = blockIdx.x * 128, m0 = blockIdx.y * 128, b = blockIdx.z;
  const int t = threadIdx.x;
  const int lane = t & 63, wave = t >> 6;
  const int col = lane & 15, quad = lane >> 4;
  const int wRow = (wave >> 1) * 64, wCol = (wave & 1) * 64;
  const unsigned short* xb = aot + (size_t)b * N_ * HID_;
  const int ldr = t >> 2;
  const int ldc8 = (((t & 3) ^ (ldr & 3)) * 8);
  const int kc = (quad ^ (col & 3)) * 8;

  f32x4 acc[4][4] = {};

#pragma unroll
  for (int call = 0; call < 2; ++call) {
    async_copy16(&W[(size_t)(m0 + call * 64 + ldr) * HID_ + ldc8],
                 &As[0][call * 2048 + t * 8]);
    async_copy16(&xb[(size_t)(n0 + call * 64 + ldr) * HID_ + ldc8],
                 &Bs[0][call * 2048 + t * 8]);
  }
  asm volatile("s_waitcnt vmcnt(0)" ::: "memory");
  __syncthreads();

  int p = 0;
  for (int k0 = 0; k0 < HID_; k0 += 32) {
    if (k0 + 32 < HID_) {
#pragma unroll
      for (int call = 0; call < 2; ++call) {
        async_copy16(&W[(size_t)(m0 + call * 64 + ldr) * HID_ + k0 + 32 + ldc8],
                     &As[p ^ 1][call * 2048 + t * 8]);
        async_copy16(&xb[(size_t)(n0 + call * 64 + ldr) * HID_ + k0 + 32 + ldc8],
                     &Bs[p ^ 1][call * 2048 + t * 8]);
      }
    }
    bf16x8 a[4], bb[4];
#pragma unroll
    for (int i = 0; i < 4; ++i)
      a[i] = *(const bf16x8*)&As[p][(wRow + i * 16 + col) * 32 + kc];
#pragma unroll
    for (int j = 0; j < 4; ++j)
      bb[j] = *(const bf16x8*)&Bs[p][(wCol + j * 16 + col) * 32 + kc];
#pragma unroll
    for (int i = 0; i < 4; ++i)
#pragma unroll
      for (int j = 0; j < 4; ++j)
        acc[i][j] = __builtin_amdgcn_mfma_f32_16x16x32_bf16(a[i], bb[j], acc[i][j], 0, 0, 0);
    asm volatile("s_waitcnt vmcnt(0)" ::: "memory");
    __syncthreads();
    p ^= 1;
  }

#pragma unroll
  for (int i = 0; i < 4; ++i) {
#pragma unroll
    for (int r = 0; r < 4; ++r) {
      int m = m0 + wRow + i * 16 + quad * 4 + r;
      float bv = bias[m];
#pragma unroll
      for (int j = 0; j < 4; ++j) {
        int n = n0 + wCol + j * 16 + col;
        out[((size_t)b * C_ + m) * N_ + n] = acc[i][j][r] + bv;
      }
    }
  }
}

extern "C" void kernel_launch(void* const* d_in, const int* in_sizes, int n_in,
                              void* d_out, int out_size, void* d_ws, size_t ws_size,
                              hipStream_t stream) {
  const float* x    = (const float*)d_in[0];
  const float* g    = (const float*)d_in[1];
  const float* Wqkv = (const float*)d_in[2];
  const float* Wout = (const float*)d_in[3];
  const float* bout = (const float*)d_in[4];
  float* out = (float*)d_out;

  unsigned short* ws  = (unsigned short*)d_ws;
  unsigned short* xnt = ws;                                  // B*N*C
  unsigned short* qt  = xnt + (size_t)B_ * N_ * C_;
  unsigned short* kt  = qt  + (size_t)B_ * H_ * N_ * D_;
  unsigned short* vt  = kt  + (size_t)B_ * H_ * N_ * D_;
  unsigned short* aot = vt  + (size_t)B_ * H_ * D_ * N_;     // B*N*HID
  unsigned short* Wqb = aot + (size_t)B_ * N_ * HID_;        // 1536*512
  unsigned short* Wob = Wqb + (size_t)3 * HID_ * C_;         // 512*512

  ln_transpose<<<dim3(N_ / 64, B_), 256, 0, stream>>>(
      x, g, xnt, Wqkv, Wqb, 3 * HID_ * C_ / 4, Wout, Wob, C_ * HID_ / 4);
  qkv_gemm<<<dim3(N_ / 128, 6, B_), 512, 0, stream>>>(Wqb, xnt, qt, kt, vt);
  attn<<<dim3(B_ * H_, N_ / 256), 512, 0, stream>>>(qt, kt, vt, aot);
  out_gemm<<<dim3(N_ / 128, 4, B_), 256, 0, stream>>>(Wob, aot, bout, out);
}